// Round 10
// baseline (308.743 us; speedup 1.0000x reference)
//
#include <hip/hip_runtime.h>
#include <hip/hip_bf16.h>

typedef _Float16 f16;
typedef _Float16 f16x8 __attribute__((ext_vector_type(8)));
typedef _Float16 f16x4 __attribute__((ext_vector_type(4)));
typedef float f32x4 __attribute__((ext_vector_type(4)));

#define MFMA_F16(a, b, c) __builtin_amdgcn_mfma_f32_16x16x32_f16((a), (b), (c), 0, 0, 0)

static constexpr int S_TOK = 2048;
static constexpr int N_HEAD = 16;
static constexpr int N_KV = 4;
static constexpr int HD = 64;
// softmax uses exp2: exp(s*0.125) == exp2(s*0.125*log2(e))
static constexpr float SCL2E = 0.125f * 1.4426950408889634f;

// ws element offsets (f16 units)
static constexpr size_t OFF_X16 = 0;                      // 4,194,304
static constexpr size_t OFF_QW = 4194304;                 // 1,048,576
static constexpr size_t OFF_KW = OFF_QW + 1048576;        // 262,144
static constexpr size_t OFF_VW = OFF_KW + 262144;         // 262,144
static constexpr size_t OFF_OW = OFF_VW + 262144;         // 1,048,576
static constexpr size_t OFF_QS = OFF_OW + 1048576;        // 4,194,304
static constexpr size_t OFF_KS = OFF_QS + 4194304;        // 1,048,576
static constexpr size_t OFF_VS = OFF_KS + 1048576;        // 1,048,576
static constexpr size_t OFF_OS = OFF_VS + 1048576;        // 4,194,304
static constexpr size_t CVT_TOTAL = OFF_OW + 1048576;     // 6,815,744 elems

// ---------------------------------------------------------------------------
// Kernel 0: fp32 -> f16 conversion of x and all four weight matrices.
// ---------------------------------------------------------------------------
__global__ __launch_bounds__(256) void k_cvt(
    const float* __restrict__ x, const float* __restrict__ qw,
    const float* __restrict__ kw, const float* __restrict__ vw,
    const float* __restrict__ ow, f16* __restrict__ dst) {
  size_t i = ((size_t)blockIdx.x * 256 + threadIdx.x) * 4;
  if (i >= CVT_TOTAL) return;
  const float* src;
  size_t off;
  if (i < OFF_QW) { src = x; off = i; }
  else if (i < OFF_KW) { src = qw; off = i - OFF_QW; }
  else if (i < OFF_VW) { src = kw; off = i - OFF_KW; }
  else if (i < OFF_OW) { src = vw; off = i - OFF_VW; }
  else { src = ow; off = i - OFF_OW; }
  float4 v = *(const float4*)(src + off);
  *(f16x4*)(dst + i) = f16x4{(f16)v.x, (f16)v.y, (f16)v.z, (f16)v.w};
}

// ---------------------------------------------------------------------------
// Kernel 1: fused QKV projection, 128x128 tile (R9, neutral-or-better).
// ---------------------------------------------------------------------------
__global__ __launch_bounds__(256) void k_qkv(
    const f16* __restrict__ x, const float* __restrict__ cosp,
    const float* __restrict__ sinp, const f16* __restrict__ q_w,
    const float* __restrict__ q_b, const f16* __restrict__ k_w,
    const f16* __restrict__ v_w, const float* __restrict__ v_b,
    f16* __restrict__ q_ws, f16* __restrict__ k_ws, f16* __restrict__ v_ws) {
  __shared__ f16 at[128][72];   // A rows x k   (+8 pad)
  __shared__ f16 bt[128][72];   // B cols(n) x k
  const int tid = threadIdx.x;
  const int wave = tid >> 6, lane = tid & 63;
  const int l16 = lane & 15, g = lane >> 4;
  const int wm = wave >> 1, wn = wave & 1;
  const int m0 = blockIdx.x * 128;
  const int n0 = blockIdx.y * 128;

  const f16* W;
  int ldW, nbase;
  if (n0 < 1024) { W = q_w; ldW = 1024; nbase = n0; }
  else if (n0 < 1280) { W = k_w; ldW = 256; nbase = n0 - 1024; }
  else { W = v_w; ldW = 256; nbase = n0 - 1280; }

  f32x4 acc[4][4] = {};
  const int arow = tid >> 3, asub = tid & 7;
  const int bkr = (tid >> 4) * 4, bnc = (tid & 15) * 4;

  for (int k0 = 0; k0 < 1024; k0 += 64) {
    f16x8 av[4];
#pragma unroll
    for (int it = 0; it < 4; ++it)
      av[it] = *(const f16x8*)(x + (size_t)(m0 + it * 32 + arow) * 1024 + k0 +
                               asub * 8);
    f16x4 bv[2][4];
#pragma unroll
    for (int it = 0; it < 2; ++it)
#pragma unroll
      for (int kk = 0; kk < 4; ++kk)
        bv[it][kk] = *(const f16x4*)(W + (size_t)(k0 + bkr + kk) * ldW + nbase +
                                     it * 64 + bnc);
    __syncthreads();
#pragma unroll
    for (int it = 0; it < 4; ++it)
      *(f16x8*)&at[it * 32 + arow][asub * 8] = av[it];
#pragma unroll
    for (int it = 0; it < 2; ++it)
#pragma unroll
      for (int i = 0; i < 4; ++i)
        *(f16x4*)&bt[it * 64 + bnc + i][bkr] =
            f16x4{bv[it][0][i], bv[it][1][i], bv[it][2][i], bv[it][3][i]};
    __syncthreads();
#pragma unroll
    for (int ks = 0; ks < 2; ++ks) {
      f16x8 af[4], bf[4];
#pragma unroll
      for (int mi = 0; mi < 4; ++mi)
        af[mi] = *(const f16x8*)&at[wm * 64 + mi * 16 + l16][ks * 32 + g * 8];
#pragma unroll
      for (int ni = 0; ni < 4; ++ni)
        bf[ni] = *(const f16x8*)&bt[wn * 64 + ni * 16 + l16][ks * 32 + g * 8];
#pragma unroll
      for (int mi = 0; mi < 4; ++mi)
#pragma unroll
        for (int ni = 0; ni < 4; ++ni)
          acc[mi][ni] = MFMA_F16(af[mi], bf[ni], acc[mi][ni]);
    }
  }

  const int gc0 = n0 + wn * 64;
  int mode, nloc;
  if (gc0 < 1024) { mode = 0; nloc = gc0; }
  else if (gc0 < 1280) { mode = 1; nloc = gc0 - 1024; }
  else { mode = 2; nloc = gc0 - 1280; }

  if (mode == 0) {
#pragma unroll
    for (int ni = 0; ni < 4; ++ni) {
      float bsc = q_b[gc0 + ni * 16 + l16];
#pragma unroll
      for (int mi = 0; mi < 4; ++mi)
#pragma unroll
        for (int r = 0; r < 4; ++r) acc[mi][ni][r] += bsc;
    }
  } else if (mode == 2) {
#pragma unroll
    for (int ni = 0; ni < 4; ++ni) {
      float bsc = v_b[nloc + ni * 16 + l16];
#pragma unroll
      for (int mi = 0; mi < 4; ++mi)
#pragma unroll
        for (int r = 0; r < 4; ++r) acc[mi][ni][r] += bsc;
    }
  }
  if (mode < 2) {
#pragma unroll
    for (int mi = 0; mi < 4; ++mi)
#pragma unroll
      for (int r = 0; r < 4; ++r) {
        int row = m0 + wm * 64 + mi * 16 + g * 4 + r;
        int bb = row >> 11, ss = row & 2047;
        float c = cosp[((size_t)bb * S_TOK + ss) * 32 + l16];
        float sn = sinp[((size_t)bb * S_TOK + ss) * 32 + l16];
        float v0 = acc[mi][0][r], v1 = acc[mi][1][r];
        acc[mi][0][r] = v0 * c - v1 * sn;
        acc[mi][1][r] = v1 * c + v0 * sn;
      }
  }
#pragma unroll
  for (int mi = 0; mi < 4; ++mi)
#pragma unroll
    for (int ni = 0; ni < 4; ++ni)
#pragma unroll
      for (int r = 0; r < 4; ++r) {
        int row = m0 + wm * 64 + mi * 16 + g * 4 + r;
        int bb = row >> 11, ss = row & 2047;
        f16 val = (f16)acc[mi][ni][r];
        if (mode == 0) {
          int col = gc0 + ni * 16 + l16;
          int h = col >> 6, hd = col & 63;
          q_ws[(((size_t)bb * N_HEAD + h) * S_TOK + ss) * HD + hd] = val;
        } else {
          int col = nloc + ni * 16 + l16;
          int kh = col >> 6, hd = col & 63;
          if (mode == 1)
            k_ws[(((size_t)bb * N_KV + kh) * S_TOK + ss) * HD + hd] = val;
          else
            v_ws[(((size_t)bb * N_KV + kh) * HD + hd) * S_TOK + ss] = val;
        }
      }
}

// ---------------------------------------------------------------------------
// Kernel 2: attention — R6 structure with TWO occupancy-only changes:
//  (a) osum OVERLAYS plds_all (epilogue-only use; extra barrier before the
//      overlay write prevents racing a still-reading pair) — LDS 36->19 KB.
//  (b) __launch_bounds__(256,4): 4 waves/SIMD (pass-B peak live ~119 VGPR,
//      should fit 128 cap without spills).
// Everything else identical to the 298-305 µs best (do not touch).
// ---------------------------------------------------------------------------
__global__ __launch_bounds__(256, 4) void k_attn(
    const f16* __restrict__ q_ws, const f16* __restrict__ k_ws,
    const f16* __restrict__ v_ws, f16* __restrict__ o_ws,
    float* __restrict__ probs) {
  __shared__ __align__(16) f16 plds_all[4][32][72];
  __shared__ float lpart[2][2][32];
  // osum overlay: [pairi][32][68] f32 (17408 B) aliases plds_all (18432 B);
  // only valid after the pre-write barrier in the epilogue.
  float(*osum)[32][68] = (float(*)[32][68])&plds_all[0][0][0];
  const int tid = threadIdx.x;
  const int wave = tid >> 6, lane = tid & 63;
  const int pairi = wave >> 1, half = wave & 1;
  const int l16 = lane & 15, g = lane >> 4;
  const int bid = blockIdx.x;
  const int combo = bid & 7, local = bid >> 3;
  const int b = combo >> 2, kvh = combo & 3;
  const int h = kvh * 4 + (local >> 5);
  const int rt = local & 31;
  const int head = b * N_HEAD + h;
  const int qrow0 = rt * 64 + pairi * 32;

  const f16* qb = q_ws + ((size_t)head * S_TOK + qrow0) * HD;
  const f16* kb = k_ws + (size_t)(b * N_KV + kvh) * S_TOK * HD;
  const f16* vb = v_ws + (size_t)(b * N_KV + kvh) * HD * S_TOK;  // [hd][s]
  float* pout = probs + (size_t)head * S_TOK * S_TOK + (size_t)qrow0 * S_TOK;
  f16(*plds)[72] = plds_all[wave];

  f16x8 qf[2][2];
#pragma unroll
  for (int mf = 0; mf < 2; ++mf)
#pragma unroll
    for (int ks = 0; ks < 2; ++ks)
      qf[mf][ks] = *(const f16x8*)(qb + (mf * 16 + l16) * HD + ks * 32 + g * 8);

  const int kt0 = half * 16, kt1 = kt0 + 16;

  // ---- pass A: partial row sums of exp over this wave's key half ----
  float lsum[2][4] = {};
  for (int kt = kt0; kt < kt1; ++kt) {
    const f16* kp = kb + (size_t)kt * 64 * HD;
#pragma unroll
    for (int n = 0; n < 4; ++n) {
      f16x8 k0f = *(const f16x8*)(kp + (n * 16 + l16) * HD + g * 8);
      f16x8 k1f = *(const f16x8*)(kp + (n * 16 + l16) * HD + 32 + g * 8);
#pragma unroll
      for (int mf = 0; mf < 2; ++mf) {
        f32x4 s = {};
        s = MFMA_F16(qf[mf][0], k0f, s);
        s = MFMA_F16(qf[mf][1], k1f, s);
#pragma unroll
        for (int r = 0; r < 4; ++r) lsum[mf][r] += exp2f(s[r] * SCL2E);
      }
    }
  }
#pragma unroll
  for (int mf = 0; mf < 2; ++mf)
#pragma unroll
    for (int r = 0; r < 4; ++r) {
      float v = lsum[mf][r];
      v += __shfl_xor(v, 1, 64);
      v += __shfl_xor(v, 2, 64);
      v += __shfl_xor(v, 4, 64);
      v += __shfl_xor(v, 8, 64);
      lsum[mf][r] = v;  // half-range row sum, replicated across 16-lane group
    }
  if (l16 == 0) {
#pragma unroll
    for (int mf = 0; mf < 2; ++mf)
#pragma unroll
      for (int r = 0; r < 4; ++r)
        lpart[pairi][half][mf * 16 + g * 4 + r] = lsum[mf][r];
  }
  __syncthreads();
  float linv[2][4];
#pragma unroll
  for (int mf = 0; mf < 2; ++mf)
#pragma unroll
    for (int r = 0; r < 4; ++r) {
      int row = mf * 16 + g * 4 + r;
      linv[mf][r] = 1.0f / (lpart[pairi][0][row] + lpart[pairi][1][row]);
    }

  // ---- pass B: probs write + partial PV ----
  f32x4 oacc[2][4] = {};
  const int orow = lane >> 4, oq = lane & 15;
  for (int kt = kt0; kt < kt1; ++kt) {
    const f16* kp = kb + (size_t)kt * 64 * HD;
#pragma unroll
    for (int n = 0; n < 4; ++n) {
      f16x8 k0f = *(const f16x8*)(kp + (n * 16 + l16) * HD + g * 8);
      f16x8 k1f = *(const f16x8*)(kp + (n * 16 + l16) * HD + 32 + g * 8);
#pragma unroll
      for (int mf = 0; mf < 2; ++mf) {
        f32x4 s = {};
        s = MFMA_F16(qf[mf][0], k0f, s);
        s = MFMA_F16(qf[mf][1], k1f, s);
#pragma unroll
        for (int r = 0; r < 4; ++r) {
          float p = exp2f(s[r] * SCL2E) * linv[mf][r];
          plds[mf * 16 + g * 4 + r][n * 16 + l16] = (f16)p;
        }
      }
    }
    asm volatile("s_waitcnt lgkmcnt(0)" ::: "memory");  // intra-wave LDS vis
    f16x8 pa[2][2];
#pragma unroll
    for (int mf = 0; mf < 2; ++mf)
#pragma unroll
      for (int ks = 0; ks < 2; ++ks)
        pa[mf][ks] = *(const f16x8*)&plds[mf * 16 + l16][ks * 32 + g * 8];
#pragma unroll
    for (int nh = 0; nh < 4; ++nh) {
      const f16* vp = vb + (size_t)(nh * 16 + l16) * S_TOK + kt * 64;
      f16x8 v0f = *(const f16x8*)(vp + g * 8);
      f16x8 v1f = *(const f16x8*)(vp + 32 + g * 8);
#pragma unroll
      for (int mf = 0; mf < 2; ++mf) {
        oacc[mf][nh] = MFMA_F16(pa[mf][0], v0f, oacc[mf][nh]);
        oacc[mf][nh] = MFMA_F16(pa[mf][1], v1f, oacc[mf][nh]);
      }
    }
    // nontemporal coalesced probs write: each inst covers 4 full 256B rows
#pragma unroll
    for (int it = 0; it < 8; ++it) {
      int rr = it * 4 + orow;
      f16x4 pv = *(const f16x4*)&plds[rr][oq * 4];
      f32x4 ov = {(float)pv[0], (float)pv[1], (float)pv[2], (float)pv[3]};
      __builtin_nontemporal_store(
          ov, (f32x4*)(pout + (size_t)rr * S_TOK + kt * 64 + oq * 4));
    }
    asm volatile("" ::: "memory");  // keep next iter's LDS writes after reads
  }

  // ---- pair O combine (osum overlays plds: barrier BEFORE the write so no
  // wave is still reading its plds region) ----
  __syncthreads();
  if (half == 1) {
#pragma unroll
    for (int mf = 0; mf < 2; ++mf)
#pragma unroll
      for (int nh = 0; nh < 4; ++nh)
#pragma unroll
        for (int r = 0; r < 4; ++r)
          osum[pairi][mf * 16 + g * 4 + r][nh * 16 + l16] = oacc[mf][nh][r];
  }
  __syncthreads();
  if (half == 0) {
#pragma unroll
    for (int mf = 0; mf < 2; ++mf)
#pragma unroll
      for (int nh = 0; nh < 4; ++nh)
#pragma unroll
        for (int r = 0; r < 4; ++r) {
          int row = mf * 16 + g * 4 + r;
          float v = oacc[mf][nh][r] + osum[pairi][row][nh * 16 + l16];
          o_ws[((size_t)b * S_TOK + qrow0 + row) * 1024 + h * HD + nh * 16 +
               l16] = (f16)v;
        }
  }
}

// ---------------------------------------------------------------------------
// Kernel 3: O projection, 128x128 tile (R9).
// ---------------------------------------------------------------------------
__global__ __launch_bounds__(256) void k_oproj(
    const f16* __restrict__ a, const f16* __restrict__ o_w,
    const float* __restrict__ o_b, float* __restrict__ out) {
  __shared__ f16 at[128][72];
  __shared__ f16 bt[128][72];
  const int tid = threadIdx.x;
  const int wave = tid >> 6, lane = tid & 63;
  const int l16 = lane & 15, g = lane >> 4;
  const int wm = wave >> 1, wn = wave & 1;
  const int m0 = blockIdx.x * 128;
  const int n0 = blockIdx.y * 128;

  f32x4 acc[4][4] = {};
  const int arow = tid >> 3, asub = tid & 7;
  const int bkr = (tid >> 4) * 4, bnc = (tid & 15) * 4;

  for (int k0 = 0; k0 < 1024; k0 += 64) {
    f16x8 av[4];
#pragma unroll
    for (int it = 0; it < 4; ++it)
      av[it] = *(const f16x8*)(a + (size_t)(m0 + it * 32 + arow) * 1024 + k0 +
                               asub * 8);
    f16x4 bv[2][4];
#pragma unroll
    for (int it = 0; it < 2; ++it)
#pragma unroll
      for (int kk = 0; kk < 4; ++kk)
        bv[it][kk] = *(const f16x4*)(o_w + (size_t)(k0 + bkr + kk) * 1024 + n0 +
                                     it * 64 + bnc);
    __syncthreads();
#pragma unroll
    for (int it = 0; it < 4; ++it)
      *(f16x8*)&at[it * 32 + arow][asub * 8] = av[it];
#pragma unroll
    for (int it = 0; it < 2; ++it)
#pragma unroll
      for (int i = 0; i < 4; ++i)
        *(f16x4*)&bt[it * 64 + bnc + i][bkr] =
            f16x4{bv[it][0][i], bv[it][1][i], bv[it][2][i], bv[it][3][i]};
    __syncthreads();
#pragma unroll
    for (int ks = 0; ks < 2; ++ks) {
      f16x8 af[4], bf[4];
#pragma unroll
      for (int mi = 0; mi < 4; ++mi)
        af[mi] = *(const f16x8*)&at[wm * 64 + mi * 16 + l16][ks * 32 + g * 8];
#pragma unroll
      for (int ni = 0; ni < 4; ++ni)
        bf[ni] = *(const f16x8*)&bt[wn * 64 + ni * 16 + l16][ks * 32 + g * 8];
#pragma unroll
      for (int mi = 0; mi < 4; ++mi)
#pragma unroll
        for (int ni = 0; ni < 4; ++ni)
          acc[mi][ni] = MFMA_F16(af[mi], bf[ni], acc[mi][ni]);
    }
  }
#pragma unroll
  for (int ni = 0; ni < 4; ++ni) {
    float bsc = o_b[n0 + wn * 64 + ni * 16 + l16];
#pragma unroll
    for (int mi = 0; mi < 4; ++mi)
#pragma unroll
      for (int r = 0; r < 4; ++r) {
        int row = m0 + wm * 64 + mi * 16 + g * 4 + r;
        out[(size_t)row * 1024 + n0 + wn * 64 + ni * 16 + l16] =
            acc[mi][ni][r] + bsc;
      }
  }
}

extern "C" void kernel_launch(void* const* d_in, const int* in_sizes, int n_in,
                              void* d_out, int out_size, void* d_ws,
                              size_t ws_size, hipStream_t stream) {
  (void)in_sizes; (void)n_in; (void)out_size; (void)ws_size;
  const float* x    = (const float*)d_in[0];
  const float* cosp = (const float*)d_in[1];
  const float* sinp = (const float*)d_in[2];
  const float* q_w  = (const float*)d_in[3];
  const float* q_b  = (const float*)d_in[4];
  const float* k_w  = (const float*)d_in[5];
  const float* v_w  = (const float*)d_in[6];
  const float* v_b  = (const float*)d_in[7];
  const float* o_w  = (const float*)d_in[8];
  const float* o_b  = (const float*)d_in[9];

  f16* ws = (f16*)d_ws;
  f16* x16  = ws + OFF_X16;
  f16* qw16 = ws + OFF_QW;
  f16* kw16 = ws + OFF_KW;
  f16* vw16 = ws + OFF_VW;
  f16* ow16 = ws + OFF_OW;
  f16* q_ws = ws + OFF_QS;
  f16* k_ws = ws + OFF_KS;
  f16* v_ws = ws + OFF_VS;
  f16* o_ws = ws + OFF_OS;
  float* out = (float*)d_out;          // attn_output [0, 4194304)
  float* probs = out + 4194304;        // attn_weights

  k_cvt<<<dim3((CVT_TOTAL / 4 + 255) / 256), 256, 0, stream>>>(
      x, q_w, k_w, v_w, o_w, ws);
  k_qkv<<<dim3(32, 12), 256, 0, stream>>>(x16, cosp, sinp, qw16, q_b, kw16,
                                          vw16, v_b, q_ws, k_ws, v_ws);
  k_attn<<<dim3(1024), 256, 0, stream>>>(q_ws, k_ws, v_ws, o_ws, probs);
  k_oproj<<<dim3(32, 8), 256, 0, stream>>>(o_ws, ow16, o_b, out);
}